// Round 1
// baseline (2025.278 us; speedup 1.0000x reference)
//
#include <hip/hip_runtime.h>
#include <float.h>

#define Bz   4
#define Cz   128
#define Nz   8192
#define Kz   20
#define OUTz 128

// ---------------------------------------------------------------------------
// Kernel 1: xx[b*N+n] = sum_c x[b][c][n]^2
// ---------------------------------------------------------------------------
__global__ __launch_bounds__(256) void xx_kernel(const float* __restrict__ x,
                                                 float* __restrict__ xx) {
    int t = blockIdx.x * 256 + threadIdx.x;          // 0 .. B*N-1
    int b = t >> 13;
    int n = t & (Nz - 1);
    const float* xp = x + (size_t)b * Cz * Nz + n;
    float s = 0.f;
#pragma unroll 8
    for (int c = 0; c < Cz; ++c) {
        float v = xp[(size_t)c * Nz];
        s = fmaf(v, v, s);
    }
    xx[t] = s;
}

// ---------------------------------------------------------------------------
// Kernel 2: fused pairwise-score GEMM + per-row top-20 (indices only).
// Grid: (N/64, B). Block 256. Each block: 64 query rows, scans all 8192 keys.
// Score s(j) = 2*dot(x_i,x_j) - xx[j]  (row-constant -xx[i] dropped; ranking
// identical to reference pd).
// Top-20 state lives in registers of owner lanes: wave w, lane l<16 owns
// row w*16+l. All unrolled static indexing -> stays in VGPRs.
// ---------------------------------------------------------------------------
__global__ __launch_bounds__(256) void knn_kernel(const float* __restrict__ x,
                                                  const float* __restrict__ xxg,
                                                  int* __restrict__ idxout) {
    const int b   = blockIdx.y;
    const int qi0 = blockIdx.x * 64;

    // 32KB + 16KB + 16KB = 64KB exactly
    __shared__ __align__(16) float xq[128 * 64];   // [c][i]
    __shared__ __align__(16) float xk[64 * 64];    // [c(chunk)][j]
    __shared__ float sc[64 * 64];                  // [i][(j+i)&63] rotated cols

    const int tid  = threadIdx.x;
    const int tx   = tid & 15;      // key group   (4 cols each)
    const int ty   = tid >> 4;      // query group (4 rows each)
    const int lane = tid & 63;
    const int wave = tid >> 6;

    const float* xb = x + (size_t)b * Cz * Nz;

    // stage the query tile once: xq[c][i] = x[b][c][qi0+i]
    {
        int li = tid & 63;
        int c0 = tid >> 6;
#pragma unroll
        for (int rep = 0; rep < 32; ++rep) {
            int c = c0 + rep * 4;
            xq[c * 64 + li] = xb[(size_t)c * Nz + qi0 + li];
        }
    }

    // per-owner top-20 state (registers; only lanes<16 of each wave use it)
    float tv[Kz];
    int   ti[Kz];
#pragma unroll
    for (int s = 0; s < Kz; ++s) { tv[s] = -FLT_MAX; ti[s] = 0; }
    float wv = -FLT_MAX;   // current worst (min) value in list
    int wslot = 0;         // its slot
    const int myrow = wave * 16 + lane;   // valid only when lane<16

    for (int kt = 0; kt < Nz / 64; ++kt) {
        const int kj0 = kt * 64;
        float acc[4][4];
#pragma unroll
        for (int di = 0; di < 4; ++di)
#pragma unroll
            for (int dj = 0; dj < 4; ++dj) acc[di][dj] = 0.f;

#pragma unroll
        for (int cc = 0; cc < 2; ++cc) {
            __syncthreads();   // previous users of xk / sc done
            {
                int lj = tid & 63;
                int c0 = tid >> 6;
#pragma unroll
                for (int rep = 0; rep < 16; ++rep) {
                    int c = c0 + rep * 4;
                    xk[c * 64 + lj] = xb[(size_t)(cc * 64 + c) * Nz + kj0 + lj];
                }
            }
            __syncthreads();
            const int aoff = ty * 4;
            const int boff = tx * 4;
#pragma unroll 8
            for (int c = 0; c < 64; ++c) {
                float4 a  = *(const float4*)&xq[(cc * 64 + c) * 64 + aoff];
                float4 bb = *(const float4*)&xk[c * 64 + boff];
                float av[4] = {a.x, a.y, a.z, a.w};
                float bv[4] = {bb.x, bb.y, bb.z, bb.w};
#pragma unroll
                for (int di = 0; di < 4; ++di)
#pragma unroll
                    for (int dj = 0; dj < 4; ++dj)
                        acc[di][dj] = fmaf(av[di], bv[dj], acc[di][dj]);
            }
        }

        // scores -> LDS (rotated column to avoid 32-way conflict on row scan)
        {
            float4 xxv = *(const float4*)&xxg[b * Nz + kj0 + tx * 4];
            float xxa[4] = {xxv.x, xxv.y, xxv.z, xxv.w};
#pragma unroll
            for (int di = 0; di < 4; ++di) {
                int row = ty * 4 + di;
#pragma unroll
                for (int dj = 0; dj < 4; ++dj) {
                    int col = tx * 4 + dj;
                    sc[row * 64 + ((col + row) & 63)] =
                        2.f * acc[di][dj] - xxa[dj];
                }
            }
        }
        __syncthreads();

        // owner-lane top-k update
        if (lane < 16) {
#pragma unroll 1
            for (int j = 0; j < 64; ++j) {
                float s = sc[myrow * 64 + ((j + myrow) & 63)];
                bool pass = s > wv;
                if (__any(pass)) {
                    if (pass) {
                        int gj = kj0 + j;
#pragma unroll
                        for (int s2 = 0; s2 < Kz; ++s2) {
                            bool hit = (s2 == wslot);
                            tv[s2] = hit ? s : tv[s2];
                            ti[s2] = hit ? gj : ti[s2];
                        }
                        wv = tv[0]; wslot = 0;
#pragma unroll
                        for (int s2 = 1; s2 < Kz; ++s2) {
                            if (tv[s2] < wv) { wv = tv[s2]; wslot = s2; }
                        }
                    }
                }
            }
        }
    }

    if (lane < 16) {
        size_t base = ((size_t)b * Nz + qi0 + myrow) * Kz;
#pragma unroll
        for (int s = 0; s < Kz; ++s) idxout[base + s] = ti[s];
    }
}

// ---------------------------------------------------------------------------
// Kernel 3: Y[p][o'] for p = b*N+n, o' in [0,256):
//   o'<128 : u = (W1+W2)^T x + bias      (W1=W[:, :C], W2=W[:, C:])
//   o'>=128: v = W2^T x
// Grid: (32768/64, 4). Block 256, 64x64 tile, 4x4 per thread, K=128.
// ---------------------------------------------------------------------------
__global__ __launch_bounds__(256) void feat_kernel(const float* __restrict__ x,
                                                   const float* __restrict__ W,
                                                   const float* __restrict__ bias,
                                                   float* __restrict__ Y) {
    const int gp0 = blockIdx.x * 64;         // global point index (b*N+n)
    const int b   = gp0 >> 13;
    const int n0  = gp0 & (Nz - 1);
    const int o0  = blockIdx.y * 64;

    __shared__ __align__(16) float xt[128 * 64];   // [c][p]
    __shared__ __align__(16) float wt[128 * 64];   // [c][o']

    const int tid = threadIdx.x;
    const int tx  = tid & 15;
    const int ty  = tid >> 4;

    {
        int li = tid & 63;
        int c0 = tid >> 6;
        const float* xbp = x + (size_t)b * Cz * Nz + n0;
#pragma unroll
        for (int rep = 0; rep < 32; ++rep) {
            int c = c0 + rep * 4;
            xt[c * 64 + li] = xbp[(size_t)c * Nz + li];
        }
    }
    {
        int lo = tid & 63;
        int c0 = tid >> 6;
        int oo = o0 + lo;
#pragma unroll
        for (int rep = 0; rep < 32; ++rep) {
            int c = c0 + rep * 4;
            float w;
            if (oo < 128) w = W[oo * 256 + c] + W[oo * 256 + 128 + c];
            else          w = W[(oo - 128) * 256 + 128 + c];
            wt[c * 64 + lo] = w;
        }
    }
    __syncthreads();

    float acc[4][4];
#pragma unroll
    for (int di = 0; di < 4; ++di)
#pragma unroll
        for (int dj = 0; dj < 4; ++dj) acc[di][dj] = 0.f;

    const int aoff = ty * 4;
    const int boff = tx * 4;
#pragma unroll 8
    for (int c = 0; c < 128; ++c) {
        float4 a  = *(const float4*)&xt[c * 64 + aoff];
        float4 ww = *(const float4*)&wt[c * 64 + boff];
        float av[4] = {a.x, a.y, a.z, a.w};
        float wvv[4] = {ww.x, ww.y, ww.z, ww.w};
#pragma unroll
        for (int di = 0; di < 4; ++di)
#pragma unroll
            for (int dj = 0; dj < 4; ++dj)
                acc[di][dj] = fmaf(av[di], wvv[dj], acc[di][dj]);
    }

    float4 bv = make_float4(0.f, 0.f, 0.f, 0.f);
    if (o0 < 128) bv = *(const float4*)&bias[o0 + tx * 4];
#pragma unroll
    for (int di = 0; di < 4; ++di) {
        float4 r;
        r.x = acc[di][0] + bv.x;
        r.y = acc[di][1] + bv.y;
        r.z = acc[di][2] + bv.z;
        r.w = acc[di][3] + bv.w;
        *(float4*)&Y[(size_t)(gp0 + ty * 4 + di) * 256 + o0 + tx * 4] = r;
    }
}

// ---------------------------------------------------------------------------
// Kernel 4: out[b][o][n] = relu(u[n][o] - min_j v[idx[n][j]][o])
// Grid: 32768/64. Block 256 = 64 points x 4 o-groups of 32.
// ---------------------------------------------------------------------------
__global__ __launch_bounds__(256) void gather_kernel(const int* __restrict__ idxg,
                                                     const float* __restrict__ Y,
                                                     float* __restrict__ out) {
    const int gp0 = blockIdx.x * 64;
    const int b   = gp0 >> 13;
    const int n0  = gp0 & (Nz - 1);

    __shared__ int lidx[64 * 21];   // pad 21 -> conflict-free row reads
    const int tid = threadIdx.x;
    for (int t = tid; t < 64 * Kz; t += 256) {
        int p = t / Kz, j = t - p * Kz;
        lidx[p * 21 + j] = idxg[(size_t)(gp0 + p) * Kz + j];
    }
    __syncthreads();

    const int p  = tid & 63;
    const int o0 = (tid >> 6) * 32;

    float mn[32];
#pragma unroll
    for (int q = 0; q < 32; ++q) mn[q] = FLT_MAX;

    for (int j = 0; j < Kz; ++j) {
        int m = lidx[p * 21 + j];
        const float4* vr =
            (const float4*)(Y + (size_t)(b * Nz + m) * 256 + 128 + o0);
#pragma unroll
        for (int q = 0; q < 8; ++q) {
            float4 v4 = vr[q];
            mn[4 * q + 0] = fminf(mn[4 * q + 0], v4.x);
            mn[4 * q + 1] = fminf(mn[4 * q + 1], v4.y);
            mn[4 * q + 2] = fminf(mn[4 * q + 2], v4.z);
            mn[4 * q + 3] = fminf(mn[4 * q + 3], v4.w);
        }
    }

    const float4* ur = (const float4*)(Y + (size_t)(gp0 + p) * 256 + o0);
#pragma unroll
    for (int q = 0; q < 8; ++q) {
        float4 u4 = ur[q];
        float r0 = fmaxf(u4.x - mn[4 * q + 0], 0.f);
        float r1 = fmaxf(u4.y - mn[4 * q + 1], 0.f);
        float r2 = fmaxf(u4.z - mn[4 * q + 2], 0.f);
        float r3 = fmaxf(u4.w - mn[4 * q + 3], 0.f);
        size_t ob = ((size_t)b * OUTz + o0 + 4 * q) * Nz + n0 + p;
        out[ob + 0 * Nz] = r0;
        out[ob + 1 * Nz] = r1;
        out[ob + 2 * Nz] = r2;
        out[ob + 3 * Nz] = r3;
    }
}

// ---------------------------------------------------------------------------
extern "C" void kernel_launch(void* const* d_in, const int* in_sizes, int n_in,
                              void* d_out, int out_size, void* d_ws, size_t ws_size,
                              hipStream_t stream) {
    const float* x    = (const float*)d_in[0];
    const float* W    = (const float*)d_in[1];
    const float* bias = (const float*)d_in[2];
    float* out = (float*)d_out;

    char* ws = (char*)d_ws;
    float* xx  = (float*)ws;                       // 128KB  @ 0
    int*   idx = (int*)(ws + (1 << 17));           // 2.5MB  @ 128KB
    float* Y   = (float*)(ws + (4 << 20));         // 32MB   @ 4MB

    xx_kernel<<<dim3(Bz * Nz / 256), dim3(256), 0, stream>>>(x, xx);

    knn_kernel<<<dim3(Nz / 64, Bz), dim3(256), 0, stream>>>(x, xx, idx);

    feat_kernel<<<dim3(Bz * Nz / 64, 4), dim3(256), 0, stream>>>(x, W, bias, Y);

    gather_kernel<<<dim3(Bz * Nz / 64), dim3(256), 0, stream>>>(idx, Y, out);
}

// Round 2
// 1345.555 us; speedup vs baseline: 1.5052x; 1.5052x over previous
//
#include <hip/hip_runtime.h>
#include <float.h>

#define Bz   4
#define Cz   128
#define Nz   8192
#define Kz   20
#define OUTz 128

// ---------------------------------------------------------------------------
// Kernel 1: xx[b*N+n] = sum_c x[b][c][n]^2   (unchanged)
// ---------------------------------------------------------------------------
__global__ __launch_bounds__(256) void xx_kernel(const float* __restrict__ x,
                                                 float* __restrict__ xx) {
    int t = blockIdx.x * 256 + threadIdx.x;          // 0 .. B*N-1
    int b = t >> 13;
    int n = t & (Nz - 1);
    const float* xp = x + (size_t)b * Cz * Nz + n;
    float s = 0.f;
#pragma unroll 8
    for (int c = 0; c < Cz; ++c) {
        float v = xp[(size_t)c * Nz];
        s = fmaf(v, v, s);
    }
    xx[t] = s;
}

// ---------------------------------------------------------------------------
// Kernel 2: fused pairwise-score GEMM + per-row top-20 (indices only).
// Grid (N/64, B), block 256. 64 query rows/block, scans all 8192 keys in
// 128-key tiles. Per-pair accumulation order (ascending c, single fmaf
// chain) is IDENTICAL to the round-1 passing kernel -> bit-identical scores.
//  - thread tile 4q x (4+4)k: cols tx*4 and 64+tx*4 (keeps each ds_read_b128
//    256B-contiguous per 16-lane phase -> no bank conflicts)
//  - xs buffer (16KB) time-shared: xk c-chunk during FMA, score tile during
//    selection. LDS total 48KB -> 3 blocks/CU.
//  - selection: owner lane reads its 64-score row as 16 x b128 (rotated by
//    4*row), builds a 64-bit candidate mask branchlessly, extracts rare
//    candidates via ffs loop. Insert semantics unchanged (strict >, ascending
//    j order -> same tie behavior; final output depends only on the SET).
// ---------------------------------------------------------------------------
__global__ __launch_bounds__(256, 3) void knn_kernel(const float* __restrict__ x,
                                                     const float* __restrict__ xxg,
                                                     int* __restrict__ idxout) {
    const int b   = blockIdx.y;
    const int qi0 = blockIdx.x * 64;

    __shared__ __align__(16) float xq[128 * 64];   // 32KB [c][q]
    __shared__ __align__(16) float xs[32 * 128];   // 16KB: xk chunk [c][k] OR sc [q][64]

    const int tid  = threadIdx.x;
    const int tx   = tid & 15;      // key group
    const int ty   = tid >> 4;      // query group (4 rows)
    const int lane = tid & 63;
    const int wave = tid >> 6;

    const float* xb = x + (size_t)b * Cz * Nz;

    // stage the query tile once: xq[c][i] = x[b][c][qi0+i]
    {
        int li = tid & 63;
        int c0 = tid >> 6;
#pragma unroll
        for (int rep = 0; rep < 32; ++rep) {
            int c = c0 + rep * 4;
            xq[c * 64 + li] = xb[(size_t)c * Nz + qi0 + li];
        }
    }

    // per-owner top-20 state (registers; lanes<16 of each wave)
    float tv[Kz];
    int   ti[Kz];
#pragma unroll
    for (int s = 0; s < Kz; ++s) { tv[s] = -FLT_MAX; ti[s] = 0; }
    float wv = -FLT_MAX;
    int wslot = 0;
    const int myrow = wave * 16 + lane;   // valid only when lane<16

    const int aoff  = ty * 4;
    const int b0off = tx * 4;
    const int b1off = 64 + tx * 4;

    for (int kt = 0; kt < Nz / 128; ++kt) {
        const int kj0 = kt * 128;
        float acc[4][8];
#pragma unroll
        for (int di = 0; di < 4; ++di)
#pragma unroll
            for (int dj = 0; dj < 8; ++dj) acc[di][dj] = 0.f;

#pragma unroll
        for (int cc = 0; cc < 4; ++cc) {
            __syncthreads();   // previous users of xs done
            // stage chunk: xs[c][k] = x[b][cc*32+c][kj0+k], 1024 float4s
#pragma unroll
            for (int r = 0; r < 4; ++r) {
                int f4 = tid + 256 * r;
                int c  = f4 >> 5;
                int k4 = (f4 & 31) * 4;
                *(float4*)&xs[c * 128 + k4] =
                    *(const float4*)&xb[(size_t)(cc * 32 + c) * Nz + kj0 + k4];
            }
            __syncthreads();
#pragma unroll 8
            for (int c = 0; c < 32; ++c) {
                float4 a = *(const float4*)&xq[(cc * 32 + c) * 64 + aoff];
                float4 p = *(const float4*)&xs[c * 128 + b0off];
                float4 q = *(const float4*)&xs[c * 128 + b1off];
                float av[4] = {a.x, a.y, a.z, a.w};
                float pv[4] = {p.x, p.y, p.z, p.w};
                float qv[4] = {q.x, q.y, q.z, q.w};
#pragma unroll
                for (int di = 0; di < 4; ++di) {
#pragma unroll
                    for (int dj = 0; dj < 4; ++dj) {
                        acc[di][dj]     = fmaf(av[di], pv[dj], acc[di][dj]);
                        acc[di][4 + dj] = fmaf(av[di], qv[dj], acc[di][4 + dj]);
                    }
                }
            }
        }
        __syncthreads();   // xs (chunk 3) fully consumed

        // two 64-col selection rounds; xs reused as score tile
#pragma unroll
        for (int h = 0; h < 2; ++h) {
            {
                float4 xxv = *(const float4*)&xxg[b * Nz + kj0 + h * 64 + tx * 4];
                float xxa[4] = {xxv.x, xxv.y, xxv.z, xxv.w};
#pragma unroll
                for (int di = 0; di < 4; ++di) {
                    int r = ty * 4 + di;
                    float4 w;
                    w.x = 2.f * acc[di][h * 4 + 0] - xxa[0];
                    w.y = 2.f * acc[di][h * 4 + 1] - xxa[1];
                    w.z = 2.f * acc[di][h * 4 + 2] - xxa[2];
                    w.w = 2.f * acc[di][h * 4 + 3] - xxa[3];
                    *(float4*)&xs[r * 64 + ((tx * 4 + 4 * r) & 63)] = w;
                }
            }
            __syncthreads();

            if (lane < 16) {
                unsigned long long pm = 0ull;
#pragma unroll
                for (int g = 0; g < 16; ++g) {
                    float4 v = *(const float4*)&xs[myrow * 64 + ((g * 4 + 4 * myrow) & 63)];
                    if (v.x > wv) pm |= 1ull << (4 * g + 0);
                    if (v.y > wv) pm |= 1ull << (4 * g + 1);
                    if (v.z > wv) pm |= 1ull << (4 * g + 2);
                    if (v.w > wv) pm |= 1ull << (4 * g + 3);
                }
                while (pm) {
                    int j = __ffsll(pm) - 1;
                    pm &= pm - 1;
                    float s = xs[myrow * 64 + ((j + 4 * myrow) & 63)];
                    if (s > wv) {   // recheck: wv may have risen
                        int gj = kj0 + h * 64 + j;
#pragma unroll
                        for (int s2 = 0; s2 < Kz; ++s2) {
                            bool hit = (s2 == wslot);
                            tv[s2] = hit ? s : tv[s2];
                            ti[s2] = hit ? gj : ti[s2];
                        }
                        wv = tv[0]; wslot = 0;
#pragma unroll
                        for (int s2 = 1; s2 < Kz; ++s2) {
                            if (tv[s2] < wv) { wv = tv[s2]; wslot = s2; }
                        }
                    }
                }
            }
            __syncthreads();   // scans done before xs is rewritten
        }
    }

    if (lane < 16) {
        size_t base = ((size_t)b * Nz + qi0 + myrow) * Kz;
#pragma unroll
        for (int s = 0; s < Kz; ++s) idxout[base + s] = ti[s];
    }
}

// ---------------------------------------------------------------------------
// Kernel 3: Y[p][o'] (unchanged)
// ---------------------------------------------------------------------------
__global__ __launch_bounds__(256) void feat_kernel(const float* __restrict__ x,
                                                   const float* __restrict__ W,
                                                   const float* __restrict__ bias,
                                                   float* __restrict__ Y) {
    const int gp0 = blockIdx.x * 64;         // global point index (b*N+n)
    const int b   = gp0 >> 13;
    const int n0  = gp0 & (Nz - 1);
    const int o0  = blockIdx.y * 64;

    __shared__ __align__(16) float xt[128 * 64];   // [c][p]
    __shared__ __align__(16) float wt[128 * 64];   // [c][o']

    const int tid = threadIdx.x;
    const int tx  = tid & 15;
    const int ty  = tid >> 4;

    {
        int li = tid & 63;
        int c0 = tid >> 6;
        const float* xbp = x + (size_t)b * Cz * Nz + n0;
#pragma unroll
        for (int rep = 0; rep < 32; ++rep) {
            int c = c0 + rep * 4;
            xt[c * 64 + li] = xbp[(size_t)c * Nz + li];
        }
    }
    {
        int lo = tid & 63;
        int c0 = tid >> 6;
        int oo = o0 + lo;
#pragma unroll
        for (int rep = 0; rep < 32; ++rep) {
            int c = c0 + rep * 4;
            float w;
            if (oo < 128) w = W[oo * 256 + c] + W[oo * 256 + 128 + c];
            else          w = W[(oo - 128) * 256 + 128 + c];
            wt[c * 64 + lo] = w;
        }
    }
    __syncthreads();

    float acc[4][4];
#pragma unroll
    for (int di = 0; di < 4; ++di)
#pragma unroll
        for (int dj = 0; dj < 4; ++dj) acc[di][dj] = 0.f;

    const int aoff = ty * 4;
    const int boff = tx * 4;
#pragma unroll 8
    for (int c = 0; c < 128; ++c) {
        float4 a  = *(const float4*)&xt[c * 64 + aoff];
        float4 ww = *(const float4*)&wt[c * 64 + boff];
        float av[4] = {a.x, a.y, a.z, a.w};
        float wvv[4] = {ww.x, ww.y, ww.z, ww.w};
#pragma unroll
        for (int di = 0; di < 4; ++di)
#pragma unroll
            for (int dj = 0; dj < 4; ++dj)
                acc[di][dj] = fmaf(av[di], wvv[dj], acc[di][dj]);
    }

    float4 bv = make_float4(0.f, 0.f, 0.f, 0.f);
    if (o0 < 128) bv = *(const float4*)&bias[o0 + tx * 4];
#pragma unroll
    for (int di = 0; di < 4; ++di) {
        float4 r;
        r.x = acc[di][0] + bv.x;
        r.y = acc[di][1] + bv.y;
        r.z = acc[di][2] + bv.z;
        r.w = acc[di][3] + bv.w;
        *(float4*)&Y[(size_t)(gp0 + ty * 4 + di) * 256 + o0 + tx * 4] = r;
    }
}

// ---------------------------------------------------------------------------
// Kernel 4: out[b][o][n] = relu(u[n][o] - min_j v[idx[n][j]][o])  (unchanged)
// ---------------------------------------------------------------------------
__global__ __launch_bounds__(256) void gather_kernel(const int* __restrict__ idxg,
                                                     const float* __restrict__ Y,
                                                     float* __restrict__ out) {
    const int gp0 = blockIdx.x * 64;
    const int b   = gp0 >> 13;
    const int n0  = gp0 & (Nz - 1);

    __shared__ int lidx[64 * 21];
    const int tid = threadIdx.x;
    for (int t = tid; t < 64 * Kz; t += 256) {
        int p = t / Kz, j = t - p * Kz;
        lidx[p * 21 + j] = idxg[(size_t)(gp0 + p) * Kz + j];
    }
    __syncthreads();

    const int p  = tid & 63;
    const int o0 = (tid >> 6) * 32;

    float mn[32];
#pragma unroll
    for (int q = 0; q < 32; ++q) mn[q] = FLT_MAX;

    for (int j = 0; j < Kz; ++j) {
        int m = lidx[p * 21 + j];
        const float4* vr =
            (const float4*)(Y + (size_t)(b * Nz + m) * 256 + 128 + o0);
#pragma unroll
        for (int q = 0; q < 8; ++q) {
            float4 v4 = vr[q];
            mn[4 * q + 0] = fminf(mn[4 * q + 0], v4.x);
            mn[4 * q + 1] = fminf(mn[4 * q + 1], v4.y);
            mn[4 * q + 2] = fminf(mn[4 * q + 2], v4.z);
            mn[4 * q + 3] = fminf(mn[4 * q + 3], v4.w);
        }
    }

    const float4* ur = (const float4*)(Y + (size_t)(gp0 + p) * 256 + o0);
#pragma unroll
    for (int q = 0; q < 8; ++q) {
        float4 u4 = ur[q];
        float r0 = fmaxf(u4.x - mn[4 * q + 0], 0.f);
        float r1 = fmaxf(u4.y - mn[4 * q + 1], 0.f);
        float r2 = fmaxf(u4.z - mn[4 * q + 2], 0.f);
        float r3 = fmaxf(u4.w - mn[4 * q + 3], 0.f);
        size_t ob = ((size_t)b * OUTz + o0 + 4 * q) * Nz + n0 + p;
        out[ob + 0 * Nz] = r0;
        out[ob + 1 * Nz] = r1;
        out[ob + 2 * Nz] = r2;
        out[ob + 3 * Nz] = r3;
    }
}

// ---------------------------------------------------------------------------
extern "C" void kernel_launch(void* const* d_in, const int* in_sizes, int n_in,
                              void* d_out, int out_size, void* d_ws, size_t ws_size,
                              hipStream_t stream) {
    const float* x    = (const float*)d_in[0];
    const float* W    = (const float*)d_in[1];
    const float* bias = (const float*)d_in[2];
    float* out = (float*)d_out;

    char* ws = (char*)d_ws;
    float* xx  = (float*)ws;                       // 128KB  @ 0
    int*   idx = (int*)(ws + (1 << 17));           // 2.5MB  @ 128KB
    float* Y   = (float*)(ws + (4 << 20));         // 32MB   @ 4MB

    xx_kernel<<<dim3(Bz * Nz / 256), dim3(256), 0, stream>>>(x, xx);

    knn_kernel<<<dim3(Nz / 64, Bz), dim3(256), 0, stream>>>(x, xx, idx);

    feat_kernel<<<dim3(Bz * Nz / 64, 4), dim3(256), 0, stream>>>(x, W, bias, Y);

    gather_kernel<<<dim3(Bz * Nz / 64), dim3(256), 0, stream>>>(idx, Y, out);
}

// Round 3
// 1328.724 us; speedup vs baseline: 1.5242x; 1.0127x over previous
//
#include <hip/hip_runtime.h>
#include <float.h>

#define Bz   4
#define Cz   128
#define Nz   8192
#define Kz   20
#define OUTz 128

// ---------------------------------------------------------------------------
// Kernel 1: xx[b*N+n] = sum_c x[b][c][n]^2   (unchanged)
// ---------------------------------------------------------------------------
__global__ __launch_bounds__(256) void xx_kernel(const float* __restrict__ x,
                                                 float* __restrict__ xx) {
    int t = blockIdx.x * 256 + threadIdx.x;          // 0 .. B*N-1
    int b = t >> 13;
    int n = t & (Nz - 1);
    const float* xp = x + (size_t)b * Cz * Nz + n;
    float s = 0.f;
#pragma unroll 8
    for (int c = 0; c < Cz; ++c) {
        float v = xp[(size_t)c * Nz];
        s = fmaf(v, v, s);
    }
    xx[t] = s;
}

// ---------------------------------------------------------------------------
// Kernel 2: fused pairwise-score GEMM + per-row top-20.
// Grid (N/64, B), block 256 (2 blocks/CU, grid-bound). Per-pair fp32 chain
// identical to round-1/2 passing kernels (ascending c, single fmaf chain)
// -> bit-identical scores and selection.
//  - double-buffered key staging (A/B 16KB each), loads issued right after
//    the barrier, consumed by ds_write at next iteration top: full overlap.
//  - score tiles alias A (cols 0..63) and B (cols 64..127) after compute.
//  - wave-parallel candidate scan: lane = (row o = lane&15, quarter p=lane>>4),
//    mask OR-combined via 64-bit shfl_xor; owner lanes (lane<16) extract with
//    recheck (same semantics as before: stale-mask superset + strict > test,
//    ascending j).
// ---------------------------------------------------------------------------
__global__ __launch_bounds__(256, 2) void knn_kernel(const float* __restrict__ x,
                                                     const float* __restrict__ xxg,
                                                     int* __restrict__ idxout) {
    const int b   = blockIdx.y;
    const int qi0 = blockIdx.x * 64;

    __shared__ __align__(16) float xq[128 * 64];    // 32KB [c][q]
    __shared__ __align__(16) float bufA[32 * 128];  // 16KB: key chunk OR h0 scores
    __shared__ __align__(16) float bufB[32 * 128];  // 16KB: key chunk OR h1 scores

    const int tid  = threadIdx.x;
    const int tx   = tid & 15;      // key group
    const int ty   = tid >> 4;      // query group (4 rows)
    const int lane = tid & 63;
    const int wave = tid >> 6;

    const float* xb = x + (size_t)b * Cz * Nz;

    // stage the query tile once: xq[c][i] = x[b][c][qi0+i]
    {
        int li = tid & 63;
        int c0 = tid >> 6;
#pragma unroll
        for (int rep = 0; rep < 32; ++rep) {
            int c = c0 + rep * 4;
            xq[c * 64 + li] = xb[(size_t)c * Nz + qi0 + li];
        }
    }

    // per-owner top-20 state (registers; lanes<16 of each wave)
    float tv[Kz];
    int   ti[Kz];
#pragma unroll
    for (int s = 0; s < Kz; ++s) { tv[s] = -FLT_MAX; ti[s] = 0; }
    float wv = -FLT_MAX;
    int wslot = 0;
    const int myrow = wave * 16 + lane;    // owner row (lane<16)
    const int srow  = wave * 16 + (lane & 15);   // scanned row (all lanes)
    const int spart = lane >> 4;                 // column quarter

    const int aoff  = ty * 4;
    const int b0off = tx * 4;
    const int b1off = 64 + tx * 4;

    // staging registers: two sets, alternated per chunk
    float4 st0[4], st1[4];

#define LOADCHUNK(dst, kj0, cc)                                               \
    {                                                                         \
        _Pragma("unroll")                                                     \
        for (int r = 0; r < 4; ++r) {                                         \
            int f4 = tid + 256 * r;                                           \
            int c  = f4 >> 5;                                                 \
            int k4 = (f4 & 31) * 4;                                           \
            dst[r] = *(const float4*)&xb[(size_t)((cc) * 32 + c) * Nz + (kj0) + k4]; \
        }                                                                     \
    }

#define WRITECHUNK(src, buf)                                                  \
    {                                                                         \
        _Pragma("unroll")                                                     \
        for (int r = 0; r < 4; ++r) {                                         \
            int f4 = tid + 256 * r;                                           \
            int c  = f4 >> 5;                                                 \
            int k4 = (f4 & 31) * 4;                                           \
            *(float4*)&buf[c * 128 + k4] = src[r];                            \
        }                                                                     \
    }

    // prologue: chunk0 of tile0 into st0
    LOADCHUNK(st0, 0, 0);

    for (int kt = 0; kt < Nz / 128; ++kt) {
        const int kj0  = kt * 128;
        const int kj0n = ((kt + 1) & (Nz / 128 - 1)) * 128;  // wrap: harmless
        float acc[4][8];
#pragma unroll
        for (int di = 0; di < 4; ++di)
#pragma unroll
            for (int dj = 0; dj < 8; ++dj) acc[di][dj] = 0.f;

#pragma unroll
        for (int cc = 0; cc < 4; ++cc) {
            float* buf = (cc & 1) ? bufB : bufA;
            if (cc & 1) { WRITECHUNK(st1, buf); } else { WRITECHUNK(st0, buf); }
            __syncthreads();
            // issue next chunk's loads (in flight across the whole compute)
            if (cc < 3) {
                if (cc & 1) { LOADCHUNK(st0, kj0, cc + 1); }
                else        { LOADCHUNK(st1, kj0, cc + 1); }
            } else {
                LOADCHUNK(st0, kj0n, 0);
            }
#pragma unroll 8
            for (int c = 0; c < 32; ++c) {
                float4 a = *(const float4*)&xq[(cc * 32 + c) * 64 + aoff];
                float4 p = *(const float4*)&buf[c * 128 + b0off];
                float4 q = *(const float4*)&buf[c * 128 + b1off];
                float av[4] = {a.x, a.y, a.z, a.w};
                float pv[4] = {p.x, p.y, p.z, p.w};
                float qv[4] = {q.x, q.y, q.z, q.w};
#pragma unroll
                for (int di = 0; di < 4; ++di) {
#pragma unroll
                    for (int dj = 0; dj < 4; ++dj) {
                        acc[di][dj]     = fmaf(av[di], pv[dj], acc[di][dj]);
                        acc[di][4 + dj] = fmaf(av[di], qv[dj], acc[di][4 + dj]);
                    }
                }
            }
        }
        __syncthreads();   // all compute reads of A/B done

        // transform -> score tiles: h0 -> bufA, h1 -> bufB (rotated cols)
        {
            float4 xx0 = *(const float4*)&xxg[b * Nz + kj0 + tx * 4];
            float4 xx1 = *(const float4*)&xxg[b * Nz + kj0 + 64 + tx * 4];
            float xxa0[4] = {xx0.x, xx0.y, xx0.z, xx0.w};
            float xxa1[4] = {xx1.x, xx1.y, xx1.z, xx1.w};
#pragma unroll
            for (int di = 0; di < 4; ++di) {
                int r = ty * 4 + di;
                int ro = (4 * tx + 4 * r) & 63;
                float4 w0, w1;
                w0.x = 2.f * acc[di][0] - xxa0[0];
                w0.y = 2.f * acc[di][1] - xxa0[1];
                w0.z = 2.f * acc[di][2] - xxa0[2];
                w0.w = 2.f * acc[di][3] - xxa0[3];
                w1.x = 2.f * acc[di][4] - xxa1[0];
                w1.y = 2.f * acc[di][5] - xxa1[1];
                w1.z = 2.f * acc[di][6] - xxa1[2];
                w1.w = 2.f * acc[di][7] - xxa1[3];
                *(float4*)&bufA[r * 64 + ro] = w0;
                *(float4*)&bufB[r * 64 + ro] = w1;
            }
        }
        __syncthreads();

        // wave-parallel candidate scan
        {
            float wvb = __shfl(wv, lane & 15);
            unsigned m0 = 0, m1 = 0;
#pragma unroll
            for (int g = 0; g < 4; ++g) {
                int col = 16 * spart + 4 * g;
                int ad  = srow * 64 + ((col + 4 * srow) & 63);
                float4 v0 = *(const float4*)&bufA[ad];
                float4 v1 = *(const float4*)&bufB[ad];
                m0 |= (unsigned)(v0.x > wvb) << (4 * g + 0);
                m0 |= (unsigned)(v0.y > wvb) << (4 * g + 1);
                m0 |= (unsigned)(v0.z > wvb) << (4 * g + 2);
                m0 |= (unsigned)(v0.w > wvb) << (4 * g + 3);
                m1 |= (unsigned)(v1.x > wvb) << (4 * g + 0);
                m1 |= (unsigned)(v1.y > wvb) << (4 * g + 1);
                m1 |= (unsigned)(v1.z > wvb) << (4 * g + 2);
                m1 |= (unsigned)(v1.w > wvb) << (4 * g + 3);
            }
            unsigned long long f0 = (unsigned long long)m0 << (16 * spart);
            unsigned long long f1 = (unsigned long long)m1 << (16 * spart);
            f0 |= __shfl_xor(f0, 16); f0 |= __shfl_xor(f0, 32);
            f1 |= __shfl_xor(f1, 16); f1 |= __shfl_xor(f1, 32);

            if (lane < 16) {
#pragma unroll
                for (int h = 0; h < 2; ++h) {
                    unsigned long long pm = h ? f1 : f0;
                    const float* sb = h ? bufB : bufA;
                    while (pm) {
                        int j = __ffsll(pm) - 1;
                        pm &= pm - 1;
                        float s = sb[myrow * 64 + ((j + 4 * myrow) & 63)];
                        if (s > wv) {   // recheck: wv may have risen
                            int gj = kj0 + h * 64 + j;
#pragma unroll
                            for (int s2 = 0; s2 < Kz; ++s2) {
                                bool hit = (s2 == wslot);
                                tv[s2] = hit ? s : tv[s2];
                                ti[s2] = hit ? gj : ti[s2];
                            }
                            wv = tv[0]; wslot = 0;
#pragma unroll
                            for (int s2 = 1; s2 < Kz; ++s2) {
                                if (tv[s2] < wv) { wv = tv[s2]; wslot = s2; }
                            }
                        }
                    }
                }
            }
        }
        __syncthreads();   // scans done before buffers are rewritten
    }

    if (lane < 16) {
        size_t base = ((size_t)b * Nz + qi0 + myrow) * Kz;
#pragma unroll
        for (int s = 0; s < Kz; ++s) idxout[base + s] = ti[s];
    }
#undef LOADCHUNK
#undef WRITECHUNK
}

// ---------------------------------------------------------------------------
// Kernel 3: Y[p][o'] (unchanged)
// ---------------------------------------------------------------------------
__global__ __launch_bounds__(256) void feat_kernel(const float* __restrict__ x,
                                                   const float* __restrict__ W,
                                                   const float* __restrict__ bias,
                                                   float* __restrict__ Y) {
    const int gp0 = blockIdx.x * 64;         // global point index (b*N+n)
    const int b   = gp0 >> 13;
    const int n0  = gp0 & (Nz - 1);
    const int o0  = blockIdx.y * 64;

    __shared__ __align__(16) float xt[128 * 64];   // [c][p]
    __shared__ __align__(16) float wt[128 * 64];   // [c][o']

    const int tid = threadIdx.x;
    const int tx  = tid & 15;
    const int ty  = tid >> 4;

    {
        int li = tid & 63;
        int c0 = tid >> 6;
        const float* xbp = x + (size_t)b * Cz * Nz + n0;
#pragma unroll
        for (int rep = 0; rep < 32; ++rep) {
            int c = c0 + rep * 4;
            xt[c * 64 + li] = xbp[(size_t)c * Nz + li];
        }
    }
    {
        int lo = tid & 63;
        int c0 = tid >> 6;
        int oo = o0 + lo;
#pragma unroll
        for (int rep = 0; rep < 32; ++rep) {
            int c = c0 + rep * 4;
            float w;
            if (oo < 128) w = W[oo * 256 + c] + W[oo * 256 + 128 + c];
            else          w = W[(oo - 128) * 256 + 128 + c];
            wt[c * 64 + lo] = w;
        }
    }
    __syncthreads();

    float acc[4][4];
#pragma unroll
    for (int di = 0; di < 4; ++di)
#pragma unroll
        for (int dj = 0; dj < 4; ++dj) acc[di][dj] = 0.f;

    const int aoff = ty * 4;
    const int boff = tx * 4;
#pragma unroll 8
    for (int c = 0; c < 128; ++c) {
        float4 a  = *(const float4*)&xt[c * 64 + aoff];
        float4 ww = *(const float4*)&wt[c * 64 + boff];
        float av[4] = {a.x, a.y, a.z, a.w};
        float wvv[4] = {ww.x, ww.y, ww.z, ww.w};
#pragma unroll
        for (int di = 0; di < 4; ++di)
#pragma unroll
            for (int dj = 0; dj < 4; ++dj)
                acc[di][dj] = fmaf(av[di], wvv[dj], acc[di][dj]);
    }

    float4 bv = make_float4(0.f, 0.f, 0.f, 0.f);
    if (o0 < 128) bv = *(const float4*)&bias[o0 + tx * 4];
#pragma unroll
    for (int di = 0; di < 4; ++di) {
        float4 r;
        r.x = acc[di][0] + bv.x;
        r.y = acc[di][1] + bv.y;
        r.z = acc[di][2] + bv.z;
        r.w = acc[di][3] + bv.w;
        *(float4*)&Y[(size_t)(gp0 + ty * 4 + di) * 256 + o0 + tx * 4] = r;
    }
}

// ---------------------------------------------------------------------------
// Kernel 4: out[b][o][n] = relu(u[n][o] - min_j v[idx[n][j]][o])  (unchanged)
// ---------------------------------------------------------------------------
__global__ __launch_bounds__(256) void gather_kernel(const int* __restrict__ idxg,
                                                     const float* __restrict__ Y,
                                                     float* __restrict__ out) {
    const int gp0 = blockIdx.x * 64;
    const int b   = gp0 >> 13;
    const int n0  = gp0 & (Nz - 1);

    __shared__ int lidx[64 * 21];
    const int tid = threadIdx.x;
    for (int t = tid; t < 64 * Kz; t += 256) {
        int p = t / Kz, j = t - p * Kz;
        lidx[p * 21 + j] = idxg[(size_t)(gp0 + p) * Kz + j];
    }
    __syncthreads();

    const int p  = tid & 63;
    const int o0 = (tid >> 6) * 32;

    float mn[32];
#pragma unroll
    for (int q = 0; q < 32; ++q) mn[q] = FLT_MAX;

    for (int j = 0; j < Kz; ++j) {
        int m = lidx[p * 21 + j];
        const float4* vr =
            (const float4*)(Y + (size_t)(b * Nz + m) * 256 + 128 + o0);
#pragma unroll
        for (int q = 0; q < 8; ++q) {
            float4 v4 = vr[q];
            mn[4 * q + 0] = fminf(mn[4 * q + 0], v4.x);
            mn[4 * q + 1] = fminf(mn[4 * q + 1], v4.y);
            mn[4 * q + 2] = fminf(mn[4 * q + 2], v4.z);
            mn[4 * q + 3] = fminf(mn[4 * q + 3], v4.w);
        }
    }

    const float4* ur = (const float4*)(Y + (size_t)(gp0 + p) * 256 + o0);
#pragma unroll
    for (int q = 0; q < 8; ++q) {
        float4 u4 = ur[q];
        float r0 = fmaxf(u4.x - mn[4 * q + 0], 0.f);
        float r1 = fmaxf(u4.y - mn[4 * q + 1], 0.f);
        float r2 = fmaxf(u4.z - mn[4 * q + 2], 0.f);
        float r3 = fmaxf(u4.w - mn[4 * q + 3], 0.f);
        size_t ob = ((size_t)b * OUTz + o0 + 4 * q) * Nz + n0 + p;
        out[ob + 0 * Nz] = r0;
        out[ob + 1 * Nz] = r1;
        out[ob + 2 * Nz] = r2;
        out[ob + 3 * Nz] = r3;
    }
}

// ---------------------------------------------------------------------------
extern "C" void kernel_launch(void* const* d_in, const int* in_sizes, int n_in,
                              void* d_out, int out_size, void* d_ws, size_t ws_size,
                              hipStream_t stream) {
    const float* x    = (const float*)d_in[0];
    const float* W    = (const float*)d_in[1];
    const float* bias = (const float*)d_in[2];
    float* out = (float*)d_out;

    char* ws = (char*)d_ws;
    float* xx  = (float*)ws;                       // 128KB  @ 0
    int*   idx = (int*)(ws + (1 << 17));           // 2.5MB  @ 128KB
    float* Y   = (float*)(ws + (4 << 20));         // 32MB   @ 4MB

    xx_kernel<<<dim3(Bz * Nz / 256), dim3(256), 0, stream>>>(x, xx);

    knn_kernel<<<dim3(Nz / 64, Bz), dim3(256), 0, stream>>>(x, xx, idx);

    feat_kernel<<<dim3(Bz * Nz / 64, 4), dim3(256), 0, stream>>>(x, W, bias, Y);

    gather_kernel<<<dim3(Bz * Nz / 64), dim3(256), 0, stream>>>(idx, Y, out);
}